// Round 8
// baseline (445.750 us; speedup 1.0000x reference)
//
#include <hip/hip_runtime.h>
#include <hip/hip_bf16.h>

constexpr int Bb = 4, Ss = 1024, Dd = 1024, Hh = 16;

typedef __attribute__((ext_vector_type(8))) short short8;
typedef __attribute__((ext_vector_type(4))) float f32x4;

static __device__ __forceinline__ ushort f2bf(float f) {
  union { __hip_bfloat16 h; ushort u; } cv;
  cv.h = __float2bfloat16(f);
  return cv.u;
}

// async global->LDS, 16B per lane. LDS dest must be wave-uniform base.
static __device__ __forceinline__ void gl_lds16(const ushort* g, ushort* l) {
  __builtin_amdgcn_global_load_lds(
      (const __attribute__((address_space(1))) void*)g,
      (__attribute__((address_space(3))) void*)l, 16, 0, 0);
}

// ---------------------------------------------------------------------------
// elementwise fp32 -> bf16 cast, 4 elems/thread
// ---------------------------------------------------------------------------
__global__ __launch_bounds__(256) void cast_f32_bf16(
    const float* __restrict__ in, ushort* __restrict__ out) {
  const int i = (blockIdx.x * 256 + threadIdx.x) * 4;
  const float4 v = *(const float4*)&in[i];
  ushort4 o;
  o.x = f2bf(v.x); o.y = f2bf(v.y); o.z = f2bf(v.z); o.w = f2bf(v.w);
  *(ushort4*)&out[i] = o;
}

// ---------------------------------------------------------------------------
// fp32 [R][C] -> bf16 [C][R]  (32x32 LDS tile transpose)
// ---------------------------------------------------------------------------
__global__ __launch_bounds__(256) void transpose_cast(
    const float* __restrict__ in, ushort* __restrict__ out, int R, int C) {
  __shared__ float T[32][33];
  const int c0 = blockIdx.x * 32, r0 = blockIdx.y * 32;
  const int t = threadIdx.x;
  const int r = t >> 3, c4 = (t & 7) * 4;
  const float4 v = *(const float4*)&in[(size_t)(r0 + r) * C + c0 + c4];
  T[r][c4 + 0] = v.x; T[r][c4 + 1] = v.y;
  T[r][c4 + 2] = v.z; T[r][c4 + 3] = v.w;
  __syncthreads();
  const int cc = t >> 3, rr4 = (t & 7) * 4;
  ushort4 o;
  o.x = f2bf(T[rr4 + 0][cc]); o.y = f2bf(T[rr4 + 1][cc]);
  o.z = f2bf(T[rr4 + 2][cc]); o.w = f2bf(T[rr4 + 3][cc]);
  *(ushort4*)&out[(size_t)(c0 + cc) * R + r0 + rr4] = o;
}

// ---------------------------------------------------------------------------
// bf16 GEMM, 2-phase double-buffered (T3 minimum recipe):
//   prologue: STAGE(buf0); barrier
//   loop:     STAGE(buf^1, t+1) issued FIRST, then ds_read+MFMA on buf,
//             then one __syncthreads
// V_SPLIT: for the QKV GEMM, blocks with n0 >= 2048 hold the V projection;
// write it TRANSPOSED straight to vt[bh][d][token] -> vtrans eliminated.
// ---------------------------------------------------------------------------
template <int BM, int BN, bool OUT_BF16, bool V_SPLIT>
__global__ __launch_bounds__(256) void gemm_bt(
    const ushort* __restrict__ A, const ushort* __restrict__ Bt,
    const float* __restrict__ bias, void* __restrict__ Cout,
    ushort* __restrict__ vt, int M, int N, int K) {
  constexpr int TM = BM / 32, TN = BN / 32;
  __shared__ ushort As[2][BM * 32];
  __shared__ ushort Bs[2][BN * 32];
  const int tid = threadIdx.x;
  const int wv = tid >> 6, lane = tid & 63;
  const int l15 = lane & 15, quad = lane >> 4;
  const int ln4 = lane >> 2, kp = (lane & 3) * 8;
  const int m0 = blockIdx.y * BM, n0 = blockIdx.x * BN;
  const int wrow = (wv >> 1) * (BM / 2), wcol = (wv & 1) * (BN / 2);

  const ushort* Arow = &A[(size_t)(m0 + wv * 16 + ln4) * K + kp];
  const ushort* Brow = &Bt[(size_t)(n0 + wv * 16 + ln4) * K + kp];

  f32x4 acc[TM][TN] = {};

  // prologue stage of tile 0
#pragma unroll
  for (int u = 0; u < BM / 64; u++)
    gl_lds16(Arow + (size_t)u * 64 * K, &As[0][wv * 512 + u * 2048]);
#pragma unroll
  for (int u = 0; u < BN / 64; u++)
    gl_lds16(Brow + (size_t)u * 64 * K, &Bs[0][wv * 512 + u * 2048]);
  __syncthreads();

  const int nt = K / 32;
  int cur = 0;
  for (int t = 0; t < nt; ++t) {
    // issue next-tile staging BEFORE compute (overlaps with MFMA below)
    if (t + 1 < nt) {
      const int k1 = (t + 1) * 32;
#pragma unroll
      for (int u = 0; u < BM / 64; u++)
        gl_lds16(Arow + (size_t)u * 64 * K + k1,
                 &As[cur ^ 1][wv * 512 + u * 2048]);
#pragma unroll
      for (int u = 0; u < BN / 64; u++)
        gl_lds16(Brow + (size_t)u * 64 * K + k1,
                 &Bs[cur ^ 1][wv * 512 + u * 2048]);
    }
    short8 af[TM], bfr[TN];
#pragma unroll
    for (int i = 0; i < TM; i++)
      af[i] = *(const short8*)&As[cur][(wrow + i * 16 + l15) * 32 + quad * 8];
#pragma unroll
    for (int j = 0; j < TN; j++)
      bfr[j] = *(const short8*)&Bs[cur][(wcol + j * 16 + l15) * 32 + quad * 8];
#pragma unroll
    for (int i = 0; i < TM; i++)
#pragma unroll
      for (int j = 0; j < TN; j++)
        acc[i][j] = __builtin_amdgcn_mfma_f32_16x16x32_bf16(af[i], bfr[j],
                                                            acc[i][j], 0, 0, 0);
    __syncthreads();  // drains vmcnt(0)+lgkmcnt(0); next tile ready
    cur ^= 1;
  }

  if (V_SPLIT && n0 >= 2048) {
    // V projection: write transposed to vt[((b*16+h)*64+d)*1024 + token]
#pragma unroll
    for (int j = 0; j < TN; j++) {
      const int col = n0 + wcol + j * 16 + l15;   // 2048..3071
      const int cv = col - 2048;
      const int hh = cv >> 6, dd = cv & 63;
      const float bv = bias[col];
#pragma unroll
      for (int i = 0; i < TM; i++) {
        const int row0 = m0 + wrow + i * 16 + quad * 4;  // 4-aligned
        const int bidx = row0 >> 10, jt = row0 & 1023;
        ushort4 o;
        o.x = f2bf(acc[i][j][0] + bv);
        o.y = f2bf(acc[i][j][1] + bv);
        o.z = f2bf(acc[i][j][2] + bv);
        o.w = f2bf(acc[i][j][3] + bv);
        *(ushort4*)&vt[((size_t)((bidx << 4) + hh) * 64 + dd) * 1024 + jt] = o;
      }
    }
  } else {
#pragma unroll
    for (int j = 0; j < TN; j++) {
      const int col = n0 + wcol + j * 16 + l15;
      const float bv = bias[col];
#pragma unroll
      for (int i = 0; i < TM; i++) {
#pragma unroll
        for (int r = 0; r < 4; r++) {
          const int row = m0 + wrow + i * 16 + quad * 4 + r;
          const float v = acc[i][j][r] + bv;
          if (OUT_BF16)
            ((ushort*)Cout)[(size_t)row * N + col] = f2bf(v);
          else
            ((float*)Cout)[(size_t)row * N + col] = v;
        }
      }
    }
  }
}

// ---------------------------------------------------------------------------
// MFMA attention. grid (S/16, B*H), block 256 = 4 waves.
// __launch_bounds__(256, 4): force VGPR <= 128 so 4 waves/SIMD are resident
// (4 blocks/CU; LDS 33 KB allows it). Hypothesis: the kernel was allocating
// >128 VGPR (64-reg sreg + unrolled address precompute) -> 2 waves/SIMD ->
// L2-gather latency and barriers half-hidden. Doubling TLP hides the stalls
// that the three null instruction-count experiments (R1/R3/R5) proved are
// NOT issue-bound.
// ---------------------------------------------------------------------------
__global__ __launch_bounds__(256, 4) void attn_mfma(
    const ushort* __restrict__ qkvb,  // [4096][3072] bf16 (Q,K thirds valid)
    const ushort* __restrict__ vt,    // [64][64][1024] bf16
    const float* __restrict__ mask,   // [4][1024]
    float* __restrict__ w_out,        // [64][1024][1024]
    ushort* __restrict__ ab) {        // [4096][1024] bf16 merged heads
  constexpr int LDP = 1032;
  __shared__ ushort Ps[16 * LDP];   // probs bf16, 33 KB
  __shared__ float PM[16][4];       // per-row per-wave maxes
  __shared__ float PSum[16][4];     // per-row per-wave sums

  // XCD swizzle (grid is 64 x 64 = 4096 blocks, x fastest in dispatch order)
  const int f = blockIdx.y * 64 + blockIdx.x;
  const int swz = (f & 7) * 512 + (f >> 3);
  const int qt = swz & 63, bh = swz >> 6;

  const int b = bh >> 4, h = bh & 15;
  const int q0 = qt * 16;
  const int tid = threadIdx.x;
  const int wv = tid >> 6, lane = tid & 63;
  const int l15 = lane & 15, quad = lane >> 4;

  // Q fragments (A operand: m = l15, k = quad*8+j)
  const size_t rowQ = (size_t)((b << 10) + q0 + l15) * 3072 + h * 64;
  const short8 qf0 = *(const short8*)&qkvb[rowQ + quad * 8];
  const short8 qf1 = *(const short8*)&qkvb[rowQ + 32 + quad * 8];

  float sreg[16][4];

  // ---- scores ----
#pragma unroll
  for (int i = 0; i < 16; i++) {
    const int j0 = (wv + 4 * i) * 16;
    const int col = j0 + l15;
    const float mv = mask[(b << 10) + col];
    if (j0 <= q0 + 15) {
      const size_t rowK = (size_t)((b << 10) + j0 + l15) * 3072 + 1024 + h * 64;
      const short8 kf0 = *(const short8*)&qkvb[rowK + quad * 8];
      const short8 kf1 = *(const short8*)&qkvb[rowK + 32 + quad * 8];
      f32x4 c = {0.f, 0.f, 0.f, 0.f};
      c = __builtin_amdgcn_mfma_f32_16x16x32_bf16(qf0, kf0, c, 0, 0, 0);
      c = __builtin_amdgcn_mfma_f32_16x16x32_bf16(qf1, kf1, c, 0, 0, 0);
#pragma unroll
      for (int r = 0; r < 4; r++)
        sreg[i][r] =
            (col <= q0 + quad * 4 + r ? c[r] * 0.125f : -10000.0f) + mv;
    } else {
#pragma unroll
      for (int r = 0; r < 4; r++) sreg[i][r] = -10000.0f + mv;
    }
  }

  // ---- row max: register -> intra-quad shuffle tree -> cross-wave LDS ----
#pragma unroll
  for (int r = 0; r < 4; r++) {
    float m = sreg[0][r];
#pragma unroll
    for (int i = 1; i < 16; i++) m = fmaxf(m, sreg[i][r]);
#pragma unroll
    for (int off = 1; off < 16; off <<= 1) m = fmaxf(m, __shfl_xor(m, off));
    if (l15 == 0) PM[quad * 4 + r][wv] = m;
  }
  __syncthreads();

  float mrow[4];
#pragma unroll
  for (int r = 0; r < 4; r++) {
    const f32x4 pm4 = *(const f32x4*)&PM[quad * 4 + r][0];
    mrow[r] = fmaxf(fmaxf(pm4[0], pm4[1]), fmaxf(pm4[2], pm4[3]));
  }

  // ---- exp (clamped) + row sum (same reduction shape) ----
  float psum[4] = {0.f, 0.f, 0.f, 0.f};
#pragma unroll
  for (int i = 0; i < 16; i++)
#pragma unroll
    for (int r = 0; r < 4; r++) {
      const float e = __expf(fminf(sreg[i][r] - mrow[r], 0.0f));
      sreg[i][r] = e;
      psum[r] += e;
    }
#pragma unroll
  for (int r = 0; r < 4; r++) {
    float s = psum[r];
#pragma unroll
    for (int off = 1; off < 16; off <<= 1) s += __shfl_xor(s, off);
    if (l15 == 0) PSum[quad * 4 + r][wv] = s;
  }
  __syncthreads();

  float inv4[4];
#pragma unroll
  for (int r = 0; r < 4; r++) {
    const f32x4 ps4 = *(const f32x4*)&PSum[quad * 4 + r][0];
    inv4[r] = 1.0f / fmaxf(ps4[0] + ps4[1] + ps4[2] + ps4[3], 1e-30f);
  }

  // ---- write w (fp32) + stash probs bf16 into LDS ----
#pragma unroll
  for (int i = 0; i < 16; i++) {
    const int j0 = (wv + 4 * i) * 16;
#pragma unroll
    for (int r = 0; r < 4; r++) {
      const float p = sreg[i][r] * inv4[r];
      w_out[((size_t)(bh << 10) + q0 + quad * 4 + r) * 1024 + j0 + l15] = p;
      Ps[(quad * 4 + r) * LDP + j0 + l15] = f2bf(p);
    }
  }
  __syncthreads();

  // ---- PV: A = Ps (A-frag m=l15, k=quad*8+j), B = Vt[bh][d][key] ----
  f32x4 oacc = {0.f, 0.f, 0.f, 0.f};
  const int nch = (q0 + 16 + 31) >> 5;
  const ushort* vbase = vt + ((size_t)bh * 64 + wv * 16 + l15) * 1024;
  for (int c = 0; c < nch; c++) {
    const int k0 = c * 32;
    const short8 pf = *(const short8*)&Ps[l15 * LDP + k0 + quad * 8];
    const short8 vf = *(const short8*)&vbase[k0 + quad * 8];
    oacc = __builtin_amdgcn_mfma_f32_16x16x32_bf16(pf, vf, oacc, 0, 0, 0);
  }
#pragma unroll
  for (int r = 0; r < 4; r++) {
    ab[(size_t)((b << 10) + q0 + quad * 4 + r) * 1024 + h * 64 + wv * 16 +
       l15] = f2bf(oacc[r]);
  }
}

// ---------------------------------------------------------------------------
extern "C" void kernel_launch(void* const* d_in, const int* in_sizes, int n_in,
                              void* d_out, int out_size, void* d_ws,
                              size_t ws_size, hipStream_t stream) {
  const float* x = (const float*)d_in[0];
  const float* mask = (const float*)d_in[1];
  const float* w_attn = (const float*)d_in[2];
  const float* b_attn = (const float*)d_in[3];
  const float* w_proj = (const float*)d_in[4];
  const float* b_proj = (const float*)d_in[5];

  float* out_a = (float*)d_out;                 // [4,1024,1024]
  float* out_w = out_a + (size_t)Bb * Ss * Dd;  // [4,16,1024,1024]

  char* ws = (char*)d_ws;
  ushort* xb   = (ushort*)(ws);                  //  8 MB
  ushort* wta  = (ushort*)(ws + (8u << 20));     //  6 MB
  ushort* wtp  = (ushort*)(ws + (14u << 20));    //  2 MB
  ushort* qkvb = (ushort*)(ws + (16u << 20));    // 24 MB (V third unused)
  ushort* vt   = (ushort*)(ws + (40u << 20));    //  8 MB
  ushort* ab   = (ushort*)(ws + (48u << 20));    //  8 MB

  cast_f32_bf16<<<(Bb * Ss * Dd) / 1024, 256, 0, stream>>>(x, xb);
  transpose_cast<<<dim3(3 * Dd / 32, Dd / 32), 256, 0, stream>>>(w_attn, wta,
                                                                 Dd, 3 * Dd);
  transpose_cast<<<dim3(Dd / 32, Dd / 32), 256, 0, stream>>>(w_proj, wtp, Dd,
                                                             Dd);
  // QKV GEMM: V third (n0 >= 2048) written transposed directly into vt.
  gemm_bt<128, 128, true, true><<<dim3(3 * Dd / 128, Bb * Ss / 128), 256, 0,
                                  stream>>>(xb, wta, b_attn, qkvb, vt,
                                            Bb * Ss, 3 * Dd, Dd);
  attn_mfma<<<dim3(Ss / 16, Bb * Hh), 256, 0, stream>>>(qkvb, vt, mask, out_w,
                                                        ab);
  // proj: BN=64 -> 512 blocks = 2 blocks/CU for implicit wave overlap.
  gemm_bt<128, 64, false, false><<<dim3(Dd / 64, Bb * Ss / 128), 256, 0,
                                   stream>>>(ab, wtp, b_proj, out_a, nullptr,
                                             Bb * Ss, Dd, Dd);
}

// Round 9
// 429.345 us; speedup vs baseline: 1.0382x; 1.0382x over previous
//
#include <hip/hip_runtime.h>
#include <hip/hip_bf16.h>

constexpr int Bb = 4, Ss = 1024, Dd = 1024, Hh = 16;

typedef __attribute__((ext_vector_type(8))) short short8;
typedef __attribute__((ext_vector_type(4))) float f32x4;

static __device__ __forceinline__ ushort f2bf(float f) {
  union { __hip_bfloat16 h; ushort u; } cv;
  cv.h = __float2bfloat16(f);
  return cv.u;
}

// async global->LDS, 16B per lane. LDS dest must be wave-uniform base.
static __device__ __forceinline__ void gl_lds16(const ushort* g, ushort* l) {
  __builtin_amdgcn_global_load_lds(
      (const __attribute__((address_space(1))) void*)g,
      (__attribute__((address_space(3))) void*)l, 16, 0, 0);
}

// ---------------------------------------------------------------------------
// elementwise fp32 -> bf16 cast, 4 elems/thread
// ---------------------------------------------------------------------------
__global__ __launch_bounds__(256) void cast_f32_bf16(
    const float* __restrict__ in, ushort* __restrict__ out) {
  const int i = (blockIdx.x * 256 + threadIdx.x) * 4;
  const float4 v = *(const float4*)&in[i];
  ushort4 o;
  o.x = f2bf(v.x); o.y = f2bf(v.y); o.z = f2bf(v.z); o.w = f2bf(v.w);
  *(ushort4*)&out[i] = o;
}

// ---------------------------------------------------------------------------
// fp32 [R][C] -> bf16 [C][R]  (32x32 LDS tile transpose)
// ---------------------------------------------------------------------------
__global__ __launch_bounds__(256) void transpose_cast(
    const float* __restrict__ in, ushort* __restrict__ out, int R, int C) {
  __shared__ float T[32][33];
  const int c0 = blockIdx.x * 32, r0 = blockIdx.y * 32;
  const int t = threadIdx.x;
  const int r = t >> 3, c4 = (t & 7) * 4;
  const float4 v = *(const float4*)&in[(size_t)(r0 + r) * C + c0 + c4];
  T[r][c4 + 0] = v.x; T[r][c4 + 1] = v.y;
  T[r][c4 + 2] = v.z; T[r][c4 + 3] = v.w;
  __syncthreads();
  const int cc = t >> 3, rr4 = (t & 7) * 4;
  ushort4 o;
  o.x = f2bf(T[rr4 + 0][cc]); o.y = f2bf(T[rr4 + 1][cc]);
  o.z = f2bf(T[rr4 + 2][cc]); o.w = f2bf(T[rr4 + 3][cc]);
  *(ushort4*)&out[(size_t)(c0 + cc) * R + r0 + rr4] = o;
}

// ---------------------------------------------------------------------------
// bf16 GEMM with T4 counted-vmcnt pipeline (3 LDS buffers, 2-deep prefetch):
//   prologue: STAGE(0), STAGE(1)            -> 2*NLD loads in flight
//   iter t:   s_waitcnt vmcnt(NLD)          -> stage(t) landed, t+1 in flight
//             s_barrier; [sched pin]
//             ds_read buf[t%3]; STAGE(t+2); MFMA
//             [sched pin]; s_barrier
// vmcnt never drains to 0 in the main loop (the m97 ~20% stall was the
// vmcnt(0) drain inside __syncthreads). Stage slack = 2 K-steps >= L2 lat.
// V_SPLIT: QKV blocks with n0 >= 2048 write V transposed straight to vt.
// ---------------------------------------------------------------------------
template <int BM, int BN, bool OUT_BF16, bool V_SPLIT>
__global__ __launch_bounds__(256) void gemm_bt(
    const ushort* __restrict__ A, const ushort* __restrict__ Bt,
    const float* __restrict__ bias, void* __restrict__ Cout,
    ushort* __restrict__ vt, int M, int N, int K) {
  constexpr int TM = BM / 32, TN = BN / 32;
  constexpr int NLD = BM / 64 + BN / 64;  // vmem instrs per stage per wave
  __shared__ ushort As[3][BM * 32];
  __shared__ ushort Bs[3][BN * 32];
  const int tid = threadIdx.x;
  const int wv = tid >> 6, lane = tid & 63;
  const int l15 = lane & 15, quad = lane >> 4;
  const int ln4 = lane >> 2, kp = (lane & 3) * 8;
  const int m0 = blockIdx.y * BM, n0 = blockIdx.x * BN;
  const int wrow = (wv >> 1) * (BM / 2), wcol = (wv & 1) * (BN / 2);

  const ushort* Arow = &A[(size_t)(m0 + wv * 16 + ln4) * K + kp];
  const ushort* Brow = &Bt[(size_t)(n0 + wv * 16 + ln4) * K + kp];

  f32x4 acc[TM][TN] = {};

  const int nt = K / 32;

#define STAGE_T(tt, buf)                                                     \
  {                                                                          \
    const int kk = (tt) * 32;                                                \
    _Pragma("unroll") for (int u = 0; u < BM / 64; u++)                      \
        gl_lds16(Arow + (size_t)u * 64 * K + kk,                             \
                 &As[buf][wv * 512 + u * 2048]);                             \
    _Pragma("unroll") for (int u = 0; u < BN / 64; u++)                      \
        gl_lds16(Brow + (size_t)u * 64 * K + kk,                             \
                 &Bs[buf][wv * 512 + u * 2048]);                             \
  }

  STAGE_T(0, 0);
  STAGE_T(1, 1);

  for (int t = 0; t < nt; ++t) {
    const int cur = t % 3;
    // wait for stage(t); keep stage(t+1)'s NLD loads in flight
    if (t + 1 < nt)
      asm volatile("s_waitcnt vmcnt(%0)" ::"n"(NLD) : "memory");
    else
      asm volatile("s_waitcnt vmcnt(0)" ::: "memory");
    __builtin_amdgcn_s_barrier();
    __builtin_amdgcn_sched_barrier(0);  // nothing crosses above this point

    short8 af[TM], bfr[TN];
#pragma unroll
    for (int i = 0; i < TM; i++)
      af[i] = *(const short8*)&As[cur][(wrow + i * 16 + l15) * 32 + quad * 8];
#pragma unroll
    for (int j = 0; j < TN; j++)
      bfr[j] = *(const short8*)&Bs[cur][(wcol + j * 16 + l15) * 32 + quad * 8];

    if (t + 2 < nt) STAGE_T(t + 2, (t + 2) % 3);

#pragma unroll
    for (int i = 0; i < TM; i++)
#pragma unroll
      for (int j = 0; j < TN; j++)
        acc[i][j] = __builtin_amdgcn_mfma_f32_16x16x32_bf16(af[i], bfr[j],
                                                            acc[i][j], 0, 0, 0);
    __builtin_amdgcn_sched_barrier(0);  // ds_reads+MFMA stay before barrier
    __builtin_amdgcn_s_barrier();
  }
#undef STAGE_T

  if (V_SPLIT && n0 >= 2048) {
    // V projection: write transposed to vt[((b*16+h)*64+d)*1024 + token]
#pragma unroll
    for (int j = 0; j < TN; j++) {
      const int col = n0 + wcol + j * 16 + l15;   // 2048..3071
      const int cv = col - 2048;
      const int hh = cv >> 6, dd = cv & 63;
      const float bv = bias[col];
#pragma unroll
      for (int i = 0; i < TM; i++) {
        const int row0 = m0 + wrow + i * 16 + quad * 4;  // 4-aligned
        const int bidx = row0 >> 10, jt = row0 & 1023;
        ushort4 o;
        o.x = f2bf(acc[i][j][0] + bv);
        o.y = f2bf(acc[i][j][1] + bv);
        o.z = f2bf(acc[i][j][2] + bv);
        o.w = f2bf(acc[i][j][3] + bv);
        *(ushort4*)&vt[((size_t)((bidx << 4) + hh) * 64 + dd) * 1024 + jt] = o;
      }
    }
  } else {
#pragma unroll
    for (int j = 0; j < TN; j++) {
      const int col = n0 + wcol + j * 16 + l15;
      const float bv = bias[col];
#pragma unroll
      for (int i = 0; i < TM; i++) {
#pragma unroll
        for (int r = 0; r < 4; r++) {
          const int row = m0 + wrow + i * 16 + quad * 4 + r;
          const float v = acc[i][j][r] + bv;
          if (OUT_BF16)
            ((ushort*)Cout)[(size_t)row * N + col] = f2bf(v);
          else
            ((float*)Cout)[(size_t)row * N + col] = v;
        }
      }
    }
  }
}

// ---------------------------------------------------------------------------
// MFMA attention (round-2/7 best structure). grid (S/16, B*H), 4 waves.
// This round: PV loop gets a 4-deep register prefetch of the V fragments —
// the previous loop consumed each L2 load (~200 cyc) serially per MFMA.
// ---------------------------------------------------------------------------
__global__ __launch_bounds__(256) void attn_mfma(
    const ushort* __restrict__ qkvb,  // [4096][3072] bf16 (Q,K thirds valid)
    const ushort* __restrict__ vt,    // [64][64][1024] bf16
    const float* __restrict__ mask,   // [4][1024]
    float* __restrict__ w_out,        // [64][1024][1024]
    ushort* __restrict__ ab) {        // [4096][1024] bf16 merged heads
  constexpr int LDP = 1032;
  __shared__ ushort Ps[16 * LDP];   // probs bf16, 33 KB
  __shared__ float PM[16][4];       // per-row per-wave maxes
  __shared__ float PSum[16][4];     // per-row per-wave sums

  // XCD swizzle (grid is 64 x 64 = 4096 blocks, x fastest in dispatch order)
  const int f = blockIdx.y * 64 + blockIdx.x;
  const int swz = (f & 7) * 512 + (f >> 3);
  const int qt = swz & 63, bh = swz >> 6;

  const int b = bh >> 4, h = bh & 15;
  const int q0 = qt * 16;
  const int tid = threadIdx.x;
  const int wv = tid >> 6, lane = tid & 63;
  const int l15 = lane & 15, quad = lane >> 4;

  // Q fragments (A operand: m = l15, k = quad*8+j)
  const size_t rowQ = (size_t)((b << 10) + q0 + l15) * 3072 + h * 64;
  const short8 qf0 = *(const short8*)&qkvb[rowQ + quad * 8];
  const short8 qf1 = *(const short8*)&qkvb[rowQ + 32 + quad * 8];

  float sreg[16][4];

  // ---- scores ----
#pragma unroll
  for (int i = 0; i < 16; i++) {
    const int j0 = (wv + 4 * i) * 16;
    const int col = j0 + l15;
    const float mv = mask[(b << 10) + col];
    if (j0 <= q0 + 15) {
      const size_t rowK = (size_t)((b << 10) + j0 + l15) * 3072 + 1024 + h * 64;
      const short8 kf0 = *(const short8*)&qkvb[rowK + quad * 8];
      const short8 kf1 = *(const short8*)&qkvb[rowK + 32 + quad * 8];
      f32x4 c = {0.f, 0.f, 0.f, 0.f};
      c = __builtin_amdgcn_mfma_f32_16x16x32_bf16(qf0, kf0, c, 0, 0, 0);
      c = __builtin_amdgcn_mfma_f32_16x16x32_bf16(qf1, kf1, c, 0, 0, 0);
#pragma unroll
      for (int r = 0; r < 4; r++)
        sreg[i][r] =
            (col <= q0 + quad * 4 + r ? c[r] * 0.125f : -10000.0f) + mv;
    } else {
#pragma unroll
      for (int r = 0; r < 4; r++) sreg[i][r] = -10000.0f + mv;
    }
  }

  // ---- row max: register -> intra-quad shuffle tree -> cross-wave LDS ----
#pragma unroll
  for (int r = 0; r < 4; r++) {
    float m = sreg[0][r];
#pragma unroll
    for (int i = 1; i < 16; i++) m = fmaxf(m, sreg[i][r]);
#pragma unroll
    for (int off = 1; off < 16; off <<= 1) m = fmaxf(m, __shfl_xor(m, off));
    if (l15 == 0) PM[quad * 4 + r][wv] = m;
  }
  __syncthreads();

  float mrow[4];
#pragma unroll
  for (int r = 0; r < 4; r++) {
    const f32x4 pm4 = *(const f32x4*)&PM[quad * 4 + r][0];
    mrow[r] = fmaxf(fmaxf(pm4[0], pm4[1]), fmaxf(pm4[2], pm4[3]));
  }

  // ---- exp (clamped) + row sum (same reduction shape) ----
  float psum[4] = {0.f, 0.f, 0.f, 0.f};
#pragma unroll
  for (int i = 0; i < 16; i++)
#pragma unroll
    for (int r = 0; r < 4; r++) {
      const float e = __expf(fminf(sreg[i][r] - mrow[r], 0.0f));
      sreg[i][r] = e;
      psum[r] += e;
    }
#pragma unroll
  for (int r = 0; r < 4; r++) {
    float s = psum[r];
#pragma unroll
    for (int off = 1; off < 16; off <<= 1) s += __shfl_xor(s, off);
    if (l15 == 0) PSum[quad * 4 + r][wv] = s;
  }
  __syncthreads();

  float inv4[4];
#pragma unroll
  for (int r = 0; r < 4; r++) {
    const f32x4 ps4 = *(const f32x4*)&PSum[quad * 4 + r][0];
    inv4[r] = 1.0f / fmaxf(ps4[0] + ps4[1] + ps4[2] + ps4[3], 1e-30f);
  }

  // ---- write w (fp32) + stash probs bf16 into LDS ----
#pragma unroll
  for (int i = 0; i < 16; i++) {
    const int j0 = (wv + 4 * i) * 16;
#pragma unroll
    for (int r = 0; r < 4; r++) {
      const float p = sreg[i][r] * inv4[r];
      w_out[((size_t)(bh << 10) + q0 + quad * 4 + r) * 1024 + j0 + l15] = p;
      Ps[(quad * 4 + r) * LDP + j0 + l15] = f2bf(p);
    }
  }
  __syncthreads();

  // ---- PV with 4-deep V prefetch: issue 4 global loads, then 4 MFMAs ----
  f32x4 oacc = {0.f, 0.f, 0.f, 0.f};
  const int nch = (q0 + 16 + 31) >> 5;
  const ushort* vbase = vt + ((size_t)bh * 64 + wv * 16 + l15) * 1024;
  for (int c0 = 0; c0 < nch; c0 += 4) {
    short8 vbuf[4];
#pragma unroll
    for (int u = 0; u < 4; u++)
      if (c0 + u < nch)
        vbuf[u] = *(const short8*)&vbase[(c0 + u) * 32 + quad * 8];
#pragma unroll
    for (int u = 0; u < 4; u++)
      if (c0 + u < nch) {
        const short8 pf =
            *(const short8*)&Ps[l15 * LDP + (c0 + u) * 32 + quad * 8];
        oacc = __builtin_amdgcn_mfma_f32_16x16x32_bf16(pf, vbuf[u], oacc,
                                                       0, 0, 0);
      }
  }
#pragma unroll
  for (int r = 0; r < 4; r++) {
    ab[(size_t)((b << 10) + q0 + quad * 4 + r) * 1024 + h * 64 + wv * 16 +
       l15] = f2bf(oacc[r]);
  }
}

// ---------------------------------------------------------------------------
extern "C" void kernel_launch(void* const* d_in, const int* in_sizes, int n_in,
                              void* d_out, int out_size, void* d_ws,
                              size_t ws_size, hipStream_t stream) {
  const float* x = (const float*)d_in[0];
  const float* mask = (const float*)d_in[1];
  const float* w_attn = (const float*)d_in[2];
  const float* b_attn = (const float*)d_in[3];
  const float* w_proj = (const float*)d_in[4];
  const float* b_proj = (const float*)d_in[5];

  float* out_a = (float*)d_out;                 // [4,1024,1024]
  float* out_w = out_a + (size_t)Bb * Ss * Dd;  // [4,16,1024,1024]

  char* ws = (char*)d_ws;
  ushort* xb   = (ushort*)(ws);                  //  8 MB
  ushort* wta  = (ushort*)(ws + (8u << 20));     //  6 MB
  ushort* wtp  = (ushort*)(ws + (14u << 20));    //  2 MB
  ushort* qkvb = (ushort*)(ws + (16u << 20));    // 24 MB (V third unused)
  ushort* vt   = (ushort*)(ws + (40u << 20));    //  8 MB
  ushort* ab   = (ushort*)(ws + (48u << 20));    //  8 MB

  cast_f32_bf16<<<(Bb * Ss * Dd) / 1024, 256, 0, stream>>>(x, xb);
  transpose_cast<<<dim3(3 * Dd / 32, Dd / 32), 256, 0, stream>>>(w_attn, wta,
                                                                 Dd, 3 * Dd);
  transpose_cast<<<dim3(Dd / 32, Dd / 32), 256, 0, stream>>>(w_proj, wtp, Dd,
                                                             Dd);
  // QKV GEMM: V third (n0 >= 2048) written transposed directly into vt.
  gemm_bt<128, 128, true, true><<<dim3(3 * Dd / 128, Bb * Ss / 128), 256, 0,
                                  stream>>>(xb, wta, b_attn, qkvb, vt,
                                            Bb * Ss, 3 * Dd, Dd);
  attn_mfma<<<dim3(Ss / 16, Bb * Hh), 256, 0, stream>>>(qkvb, vt, mask, out_w,
                                                        ab);
  // proj: BN=64 -> 512 blocks = 2 blocks/CU for implicit wave overlap.
  gemm_bt<128, 64, false, false><<<dim3(Dd / 64, Bb * Ss / 128), 256, 0,
                                   stream>>>(ab, wtp, b_proj, out_a, nullptr,
                                             Bb * Ss, Dd, Dd);
}